// Round 1
// baseline (279.595 us; speedup 1.0000x reference)
//
#include <hip/hip_runtime.h>

namespace {

constexpr int NTAGS = 64;
constexpr int START_T = 62;
constexpr int STOP_T = 63;
constexpr float NEGV = -10000.0f;
constexpr int Bc = 512;
constexpr int Lc = 512;

__device__ __forceinline__ float readlane_f(float v, int srclane) {
  return __int_as_float(__builtin_amdgcn_readlane(__float_as_int(v), srclane));
}

__device__ __forceinline__ float wave_max(float v) {
#pragma unroll
  for (int off = 32; off >= 1; off >>= 1)
    v = fmaxf(v, __shfl_xor(v, off, 64));
  return v;
}

__device__ __forceinline__ float wave_sum(float v) {
#pragma unroll
  for (int off = 32; off >= 1; off >>= 1)
    v += __shfl_xor(v, off, 64);
  return v;
}

// One wave (64 lanes) per batch element. lane = tag index i.
// alpha held per-lane; E[i][:] = exp(trans[i][:]) in 64 VGPRs per lane.
__global__ __launch_bounds__(64, 1) void crf_scan(
    const float* __restrict__ inputs,   // [B, L, 64]
    const int* __restrict__ tags,       // [B, L]
    const int* __restrict__ mask,       // [B, L]
    const float* __restrict__ trans,    // [64, 64]
    float* __restrict__ partial) {      // [B]
  const int b = blockIdx.x;
  const int lane = threadIdx.x;

  // Precompute E[j] = exp(trans[lane][j]) into registers (fully static idx).
  float E[NTAGS];
  {
    const float4* row = reinterpret_cast<const float4*>(trans + lane * NTAGS);
#pragma unroll
    for (int q = 0; q < NTAGS / 4; ++q) {
      float4 t = row[q];
      E[4 * q + 0] = __expf(t.x);
      E[4 * q + 1] = __expf(t.y);
      E[4 * q + 2] = __expf(t.z);
      E[4 * q + 3] = __expf(t.w);
    }
  }

  const float* emit_base = inputs + (size_t)b * Lc * NTAGS;
  const int* mask_b = mask + b * Lc;
  const int* tags_b = tags + b * Lc;

  float alpha = (lane == START_T) ? 0.0f : NEGV;
  float m = 0.0f;  // running max of alpha across lanes
  float emit = emit_base[lane];  // l = 0, coalesced

  for (int l = 0; l < Lc; ++l) {
    // software-pipeline next emit load (independent of this step's compute)
    float emit_nxt = 0.0f;
    if (l + 1 < Lc) emit_nxt = emit_base[(size_t)(l + 1) * NTAGS + lane];
    const int mv = mask_b[l];  // wave-uniform

    float u = __expf(alpha - m);  // in (0, 1]; dead paths underflow to 0

    if (mv != 0) {
      // alpha'[i] = log( sum_j E[i][j] * u[j] ) + m + emit[i]
      float a0 = 0.f, a1 = 0.f, a2 = 0.f, a3 = 0.f;
#pragma unroll
      for (int j = 0; j < NTAGS; j += 4) {
        a0 = fmaf(readlane_f(u, j + 0), E[j + 0], a0);
        a1 = fmaf(readlane_f(u, j + 1), E[j + 1], a1);
        a2 = fmaf(readlane_f(u, j + 2), E[j + 2], a2);
        a3 = fmaf(readlane_f(u, j + 3), E[j + 3], a3);
      }
      float s = (a0 + a1) + (a2 + a3);
      alpha = __logf(s) + m + emit;
    } else {
      // mask==0: scores[i,j] = alpha[j] -> logsumexp_j alpha, same for all i
      float s = wave_sum(u);
      alpha = __logf(s) + m;
    }
    m = wave_max(alpha);
    emit = emit_nxt;
  }

  // log denominator: logsumexp(alpha + trans[STOP, :])
  float term = alpha + trans[STOP_T * NTAGS + lane];
  float mx = wave_max(term);
  float sden = wave_sum(__expf(term - mx));
  float logden = mx + __logf(sden);

  // numerator score: lanes parallel over timesteps
  float sc = 0.0f;
  for (int l = lane; l < Lc; l += 64) {
    int tl = tags_b[l];
    float mfl = (float)mask_b[l];
    if (l < Lc - 1) {
      int tn = tags_b[l + 1];
      float mfn = (float)mask_b[l + 1];
      sc += trans[tn * NTAGS + tl] * mfn +
            emit_base[(size_t)l * NTAGS + tl] * mfl;
    } else {
      sc += trans[STOP_T * NTAGS + tl] +
            emit_base[(size_t)l * NTAGS + tl] * mfl;
    }
  }
  if (lane == 0) sc += trans[tags_b[0] * NTAGS + START_T];
  float score = wave_sum(sc);

  if (lane == 0) partial[b] = score - logden;
}

__global__ void crf_reduce(const float* __restrict__ partial,
                           float* __restrict__ out) {
  const int lane = threadIdx.x;
  float s = 0.0f;
  for (int i = lane; i < Bc; i += 64) s += partial[i];
  s = wave_sum(s);
  if (lane == 0) out[0] = s;
}

}  // namespace

extern "C" void kernel_launch(void* const* d_in, const int* in_sizes, int n_in,
                              void* d_out, int out_size, void* d_ws,
                              size_t ws_size, hipStream_t stream) {
  const float* inputs = (const float*)d_in[0];
  const int* tags = (const int*)d_in[1];
  const int* mask = (const int*)d_in[2];
  const float* trans = (const float*)d_in[3];
  float* out = (float*)d_out;
  float* partial = (float*)d_ws;  // B floats of scratch

  crf_scan<<<Bc, 64, 0, stream>>>(inputs, tags, mask, trans, partial);
  crf_reduce<<<1, 64, 0, stream>>>(partial, out);
}

// Round 2
// 162.134 us; speedup vs baseline: 1.7245x; 1.7245x over previous
//
#include <hip/hip_runtime.h>

namespace {

typedef float v2f __attribute__((ext_vector_type(2)));

constexpr int NTAGS = 64;
constexpr int START_T = 62;
constexpr int STOP_T = 63;
constexpr float NEGV = -10000.0f;
constexpr int Bc = 512;
constexpr int Lc = 512;

__device__ __forceinline__ float rfl_f(float v) {
  return __int_as_float(__builtin_amdgcn_readfirstlane(__float_as_int(v)));
}

__device__ __forceinline__ float wave_max(float v) {
#pragma unroll
  for (int off = 32; off >= 1; off >>= 1)
    v = fmaxf(v, __shfl_xor(v, off, 64));
  return v;
}

__device__ __forceinline__ float wave_sum(float v) {
#pragma unroll
  for (int off = 32; off >= 1; off >>= 1)
    v += __shfl_xor(v, off, 64);
  return v;
}

// One wave (64 lanes) per batch element. lane = tag index i.
// E row i (= exp(trans[i][:])) lives in 32 named v2f registers of lane i.
// Per step: u_j = exp(alpha_j - m) broadcast through LDS (same-address
// float4 reads), 32 v_pk_fma_f32, log, m via readfirstlane (no wave_max).
__global__ __launch_bounds__(64, 1) void crf_scan(
    const float* __restrict__ inputs,   // [B, L, 64]
    const int* __restrict__ tags,       // [B, L]
    const int* __restrict__ mask,       // [B, L]
    const float* __restrict__ trans,    // [64, 64]
    float* __restrict__ partial) {      // [B]
  __shared__ float4 u4[16];
  float* u1 = reinterpret_cast<float*>(u4);

  const int b = blockIdx.x;
  const int lane = threadIdx.x;

#define FOR16(X) X(0) X(1) X(2) X(3) X(4) X(5) X(6) X(7) \
                 X(8) X(9) X(10) X(11) X(12) X(13) X(14) X(15)

  // --- E in named registers (no array -> guaranteed VGPR allocation) ---
#define DECL_E(q) v2f Ea##q, Eb##q;
  FOR16(DECL_E)
  {
    const float4* row = reinterpret_cast<const float4*>(trans + lane * NTAGS);
#define LOAD_E(q)                                     \
    {                                                 \
      float4 t = row[q];                              \
      Ea##q = (v2f){__expf(t.x), __expf(t.y)};        \
      Eb##q = (v2f){__expf(t.z), __expf(t.w)};        \
    }
    FOR16(LOAD_E)
  }

  const float* emit_base = inputs + (size_t)b * Lc * NTAGS;
  const float* pe = emit_base + lane;
  const int* mask_b = mask + b * Lc;
  const int* tags_b = tags + b * Lc;

  float alpha = (lane == START_T) ? 0.0f : NEGV;
  float m = 0.0f;

  // matvec: acc += E * u, packed. 4 accumulators (2 v2f chains each 8 deep).
#define MF(q, A, B)                                   \
    {                                                 \
      float4 uu = u4[q];                              \
      A += Ea##q * (v2f){uu.x, uu.y};                 \
      B += Eb##q * (v2f){uu.z, uu.w};                 \
    }
#define MS(q)                                         \
    {                                                 \
      float4 uu = u4[q];                              \
      a0 += (v2f){uu.x, uu.y};                        \
      a1 += (v2f){uu.z, uu.w};                        \
    }

#define STEP(EMIT, MIDX)                                              \
    {                                                                 \
      float u_ = __expf(alpha - m);                                   \
      u1[lane] = u_;                                                  \
      __builtin_amdgcn_wave_barrier();                                \
      int mv = __builtin_amdgcn_readlane(mrow, (MIDX));               \
      if (mv) {                                                       \
        v2f a0 = {0.f, 0.f}, a1 = {0.f, 0.f};                         \
        v2f a2 = {0.f, 0.f}, a3 = {0.f, 0.f};                         \
        MF(0, a0, a1) MF(1, a2, a3) MF(2, a0, a1) MF(3, a2, a3)       \
        MF(4, a0, a1) MF(5, a2, a3) MF(6, a0, a1) MF(7, a2, a3)       \
        MF(8, a0, a1) MF(9, a2, a3) MF(10, a0, a1) MF(11, a2, a3)     \
        MF(12, a0, a1) MF(13, a2, a3) MF(14, a0, a1) MF(15, a2, a3)   \
        v2f t = (a0 + a1) + (a2 + a3);                                \
        alpha = __logf(t.x + t.y) + m + (EMIT);                       \
      } else {                                                        \
        v2f a0 = {0.f, 0.f}, a1 = {0.f, 0.f};                         \
        MS(0) MS(1) MS(2) MS(3) MS(4) MS(5) MS(6) MS(7)               \
        MS(8) MS(9) MS(10) MS(11) MS(12) MS(13) MS(14) MS(15)         \
        v2f t = a0 + a1;                                              \
        alpha = __logf(t.x + t.y) + m;                                \
      }                                                               \
      __builtin_amdgcn_wave_barrier();                                \
      m = rfl_f(alpha);                                               \
    }

  // emit prefetch: two banks of 4 named scalars, distance 4-8 steps.
#define PRE(B0, B1, B2, B3, ST)                                       \
    {                                                                 \
      int s_ = (ST); s_ = s_ > (Lc - 4) ? (Lc - 4) : s_;              \
      B0 = pe[(size_t)(s_ + 0) * NTAGS];                              \
      B1 = pe[(size_t)(s_ + 1) * NTAGS];                              \
      B2 = pe[(size_t)(s_ + 2) * NTAGS];                              \
      B3 = pe[(size_t)(s_ + 3) * NTAGS];                              \
    }

  float eA0, eA1, eA2, eA3, eB0, eB1, eB2, eB3;
  PRE(eA0, eA1, eA2, eA3, 0)
  int mrow = mask_b[lane];

  for (int chunk = 0; chunk < 8; ++chunk) {
    const int cbase = chunk * 64;
    int mrow_nxt = mask_b[(chunk < 7 ? cbase + 64 : cbase) + lane];
    for (int gp = 0; gp < 8; ++gp) {
      const int base = cbase + gp * 8;
      const int mb = gp * 8;
      PRE(eB0, eB1, eB2, eB3, base + 4)
      STEP(eA0, mb + 0) STEP(eA1, mb + 1) STEP(eA2, mb + 2) STEP(eA3, mb + 3)
      PRE(eA0, eA1, eA2, eA3, base + 8)
      STEP(eB0, mb + 4) STEP(eB1, mb + 5) STEP(eB2, mb + 6) STEP(eB3, mb + 7)
    }
    mrow = mrow_nxt;
  }

  // log denominator: logsumexp(alpha + trans[STOP, :])
  float term = alpha + trans[STOP_T * NTAGS + lane];
  float mx = wave_max(term);
  float sden = wave_sum(__expf(term - mx));
  float logden = mx + __logf(sden);

  // numerator score: lanes parallel over timesteps
  float sc = 0.0f;
  for (int l = lane; l < Lc; l += 64) {
    int tl = tags_b[l];
    float mfl = (float)mask_b[l];
    if (l < Lc - 1) {
      int tn = tags_b[l + 1];
      float mfn = (float)mask_b[l + 1];
      sc += trans[tn * NTAGS + tl] * mfn +
            emit_base[(size_t)l * NTAGS + tl] * mfl;
    } else {
      sc += trans[STOP_T * NTAGS + tl] +
            emit_base[(size_t)l * NTAGS + tl] * mfl;
    }
  }
  if (lane == 0) sc += trans[tags_b[0] * NTAGS + START_T];
  float score = wave_sum(sc);

  if (lane == 0) partial[b] = score - logden;
}

__global__ void crf_reduce(const float* __restrict__ partial,
                           float* __restrict__ out) {
  const int lane = threadIdx.x;
  float s = 0.0f;
  for (int i = lane; i < Bc; i += 64) s += partial[i];
  s = wave_sum(s);
  if (lane == 0) out[0] = s;
}

}  // namespace

extern "C" void kernel_launch(void* const* d_in, const int* in_sizes, int n_in,
                              void* d_out, int out_size, void* d_ws,
                              size_t ws_size, hipStream_t stream) {
  const float* inputs = (const float*)d_in[0];
  const int* tags = (const int*)d_in[1];
  const int* mask = (const int*)d_in[2];
  const float* trans = (const float*)d_in[3];
  float* out = (float*)d_out;
  float* partial = (float*)d_ws;  // B floats of scratch

  crf_scan<<<Bc, 64, 0, stream>>>(inputs, tags, mask, trans, partial);
  crf_reduce<<<1, 64, 0, stream>>>(partial, out);
}

// Round 3
// 152.052 us; speedup vs baseline: 1.8388x; 1.0663x over previous
//
#include <hip/hip_runtime.h>

namespace {

typedef float v2f __attribute__((ext_vector_type(2)));

constexpr int NTAGS = 64;
constexpr int START_T = 62;
constexpr int STOP_T = 63;
constexpr int Bc = 512;
constexpr int Lc = 512;

__device__ __forceinline__ float wave_max(float v) {
#pragma unroll
  for (int off = 32; off >= 1; off >>= 1)
    v = fmaxf(v, __shfl_xor(v, off, 64));
  return v;
}

__device__ __forceinline__ float wave_sum(float v) {
#pragma unroll
  for (int off = 32; off >= 1; off >>= 1)
    v += __shfl_xor(v, off, 64);
  return v;
}

// One wave per batch element; lane = tag i.
// State: v_i = exp(alpha_i - M), M = Msum*ln2 (Msum exact integer).
// Step (exp-domain, no transcendentals on the critical path):
//   s_i = sum_j E_ij v_j          (E = exp(trans), in registers)
//   v'_i = s_i * w_i * r          (w_i = exp(emit_i), prefetched+precomputed)
//   r = 2^(127-exp(s_0)) via SALU bit math; Msum += exp(s_0)-127
__global__ __launch_bounds__(64, 1) void crf_scan(
    const float* __restrict__ inputs,   // [B, L, 64]
    const int* __restrict__ tags,       // [B, L]
    const int* __restrict__ mask,       // [B, L]
    const float* __restrict__ trans,    // [64, 64]
    float* __restrict__ partial) {      // [B]
  __shared__ float4 vb4[16];
  float* vb1 = reinterpret_cast<float*>(vb4);

  const int b = blockIdx.x;
  const int lane = threadIdx.x;

#define FOR16(X) X(0) X(1) X(2) X(3) X(4) X(5) X(6) X(7) \
                 X(8) X(9) X(10) X(11) X(12) X(13) X(14) X(15)

  // --- E = exp(trans[lane][:]) in named registers ---
#define DECL_E(q) v2f Ea##q, Eb##q;
  FOR16(DECL_E)
  {
    const float4* row = reinterpret_cast<const float4*>(trans + lane * NTAGS);
#define LOAD_E(q)                                     \
    {                                                 \
      float4 t = row[q];                              \
      Ea##q = (v2f){__expf(t.x), __expf(t.y)};        \
      Eb##q = (v2f){__expf(t.z), __expf(t.w)};        \
    }
    FOR16(LOAD_E)
  }

  const float* emit_base = inputs + (size_t)b * Lc * NTAGS;
  const float* pe = emit_base + lane;
  const int* mask_b = mask + b * Lc;
  const int* tags_b = tags + b * Lc;

  int Msum = 0;  // wave-uniform exact log2 offset accumulator
  vb1[lane] = (lane == START_T) ? 1.0f : 0.0f;
  __builtin_amdgcn_wave_barrier();

#define MF(q, A, Bq)                                  \
    {                                                 \
      float4 uu = vb4[q];                             \
      A += Ea##q * (v2f){uu.x, uu.y};                 \
      Bq += Eb##q * (v2f){uu.z, uu.w};                \
    }
#define MS(q)                                         \
    {                                                 \
      float4 uu = vb4[q];                             \
      a0 += (v2f){uu.x, uu.y};                        \
      a1 += (v2f){uu.z, uu.w};                        \
    }

#define STEP(W, MIDX)                                                 \
    {                                                                 \
      const int mv = __builtin_amdgcn_readlane(mrow, (MIDX));         \
      float s;                                                        \
      if (mv) {                                                       \
        v2f a0 = {0.f, 0.f}, a1 = {0.f, 0.f};                         \
        v2f a2 = {0.f, 0.f}, a3 = {0.f, 0.f};                         \
        MF(0, a0, a1) MF(1, a2, a3) MF(2, a0, a1) MF(3, a2, a3)       \
        MF(4, a0, a1) MF(5, a2, a3) MF(6, a0, a1) MF(7, a2, a3)       \
        MF(8, a0, a1) MF(9, a2, a3) MF(10, a0, a1) MF(11, a2, a3)     \
        MF(12, a0, a1) MF(13, a2, a3) MF(14, a0, a1) MF(15, a2, a3)   \
        v2f t = (a0 + a1) + (a2 + a3);                                \
        s = (t.x + t.y) * (W);                                        \
      } else {                                                        \
        v2f a0 = {0.f, 0.f}, a1 = {0.f, 0.f};                         \
        MS(0) MS(1) MS(2) MS(3) MS(4) MS(5) MS(6) MS(7)               \
        MS(8) MS(9) MS(10) MS(11) MS(12) MS(13) MS(14) MS(15)         \
        v2f t = a0 + a1;                                              \
        s = t.x + t.y;                                                \
      }                                                               \
      const unsigned sb =                                             \
          (unsigned)__builtin_amdgcn_readfirstlane(__float_as_int(s));\
      const unsigned e0 = (sb >> 23) & 0xffu;                         \
      Msum += (int)e0 - 127;                                          \
      const float r = __uint_as_float((254u - e0) << 23);             \
      const float vv = s * r;                                         \
      __builtin_amdgcn_wave_barrier();                                \
      vb1[lane] = vv;                                                 \
      __builtin_amdgcn_wave_barrier();                                \
    }

  // w = exp(emit) prefetch: two banks of 4, distance 4-8 steps.
#define PRE(B0, B1, B2, B3, ST)                                       \
    {                                                                 \
      int s_ = (ST); s_ = s_ > (Lc - 4) ? (Lc - 4) : s_;              \
      B0 = __expf(pe[(size_t)(s_ + 0) * NTAGS]);                      \
      B1 = __expf(pe[(size_t)(s_ + 1) * NTAGS]);                      \
      B2 = __expf(pe[(size_t)(s_ + 2) * NTAGS]);                      \
      B3 = __expf(pe[(size_t)(s_ + 3) * NTAGS]);                      \
    }

  float eA0, eA1, eA2, eA3, eB0, eB1, eB2, eB3;
  PRE(eA0, eA1, eA2, eA3, 0)
  int mrow = mask_b[lane];

  for (int chunk = 0; chunk < 8; ++chunk) {
    const int cbase = chunk * 64;
    int mrow_nxt = mask_b[(chunk < 7 ? cbase + 64 : cbase) + lane];
    for (int gp = 0; gp < 8; ++gp) {
      const int base = cbase + gp * 8;
      const int mb = gp * 8;
      PRE(eB0, eB1, eB2, eB3, base + 4)
      STEP(eA0, mb + 0) STEP(eA1, mb + 1) STEP(eA2, mb + 2) STEP(eA3, mb + 3)
      PRE(eA0, eA1, eA2, eA3, base + 8)
      STEP(eB0, mb + 4) STEP(eB1, mb + 5) STEP(eB2, mb + 6) STEP(eB3, mb + 7)
    }
    mrow = mrow_nxt;
  }

  // ---- epilogue ----
  // C = Msum * ln2, exact hi/lo split (ln2_hi has 9 mantissa bits).
  const float mf = (float)Msum;
  const float C = fmaf(mf, -2.1219444e-4f, mf * 0.693359375f);

  float alphav = __logf(vb1[lane]) + C;
  float term = alphav + trans[STOP_T * NTAGS + lane];
  float mx = wave_max(term);
  float sden = wave_sum(__expf(term - mx));
  float logden = mx + __logf(sden);

  // numerator score: lanes parallel over timesteps (exact, unchanged)
  float sc = 0.0f;
  for (int l = lane; l < Lc; l += 64) {
    int tl = tags_b[l];
    float mfl = (float)mask_b[l];
    if (l < Lc - 1) {
      int tn = tags_b[l + 1];
      float mfn = (float)mask_b[l + 1];
      sc += trans[tn * NTAGS + tl] * mfn +
            emit_base[(size_t)l * NTAGS + tl] * mfl;
    } else {
      sc += trans[STOP_T * NTAGS + tl] +
            emit_base[(size_t)l * NTAGS + tl] * mfl;
    }
  }
  if (lane == 0) sc += trans[tags_b[0] * NTAGS + START_T];
  float score = wave_sum(sc);

  if (lane == 0) partial[b] = score - logden;
}

__global__ void crf_reduce(const float* __restrict__ partial,
                           float* __restrict__ out) {
  const int lane = threadIdx.x;
  float s = 0.0f;
  for (int i = lane; i < Bc; i += 64) s += partial[i];
  s = wave_sum(s);
  if (lane == 0) out[0] = s;
}

}  // namespace

extern "C" void kernel_launch(void* const* d_in, const int* in_sizes, int n_in,
                              void* d_out, int out_size, void* d_ws,
                              size_t ws_size, hipStream_t stream) {
  const float* inputs = (const float*)d_in[0];
  const int* tags = (const int*)d_in[1];
  const int* mask = (const int*)d_in[2];
  const float* trans = (const float*)d_in[3];
  float* out = (float*)d_out;
  float* partial = (float*)d_ws;  // B floats of scratch

  crf_scan<<<Bc, 64, 0, stream>>>(inputs, tags, mask, trans, partial);
  crf_reduce<<<1, 64, 0, stream>>>(partial, out);
}